// Round 1
// baseline (192.764 us; speedup 1.0000x reference)
//
#include <hip/hip_runtime.h>
#include <math.h>

// Max-pool over gathered neighbor features.
//   features: (N, F=128) f32, neighbor_indices: (NP, K=32) i32
//   out: (NP, F=128) f32 = max over K of features[idx[p][k]][:]
//
// Layout choice: 32-lane group per output point, lane l owns float4 #l of the
// 128-float row (32 x float4 = 128 floats). Per neighbor the group issues a
// fully-coalesced 512 B burst (one feature row). Lane l preloads index k=l,
// broadcast per-iteration via __shfl width=32.

__global__ __launch_bounds__(256) void pool_max_kernel(
    const float4* __restrict__ feat4,   // (N, 32) rows of float4
    const int*    __restrict__ nbr,     // (NP, 32)
    float4*       __restrict__ out4,    // (NP, 32)
    int NP)
{
    int gid = blockIdx.x * blockDim.x + threadIdx.x;
    int p = gid >> 5;          // output point
    int l = gid & 31;          // lane within group
    if (p >= NP) return;

    // each lane loads one of the 32 neighbor indices for this point
    int myidx = nbr[p * 32 + l];

    float4 m = make_float4(-INFINITY, -INFINITY, -INFINITY, -INFINITY);
#pragma unroll 8
    for (int k = 0; k < 32; ++k) {
        int j = __shfl(myidx, k, 32);            // broadcast neighbor k's row index
        float4 v = feat4[(size_t)j * 32 + l];    // coalesced 512 B burst per group
        m.x = fmaxf(m.x, v.x);
        m.y = fmaxf(m.y, v.y);
        m.z = fmaxf(m.z, v.z);
        m.w = fmaxf(m.w, v.w);
    }
    out4[(size_t)p * 32 + l] = m;
}

extern "C" void kernel_launch(void* const* d_in, const int* in_sizes, int n_in,
                              void* d_out, int out_size, void* d_ws, size_t ws_size,
                              hipStream_t stream) {
    // inputs: [0] points (N,3) f32 (unused), [1] features (N,128) f32,
    //         [2] neighbor_indices (NP,32) i32
    const float* features = (const float*)d_in[1];
    const int*   nbr      = (const int*)d_in[2];
    float*       out      = (float*)d_out;

    const int F = 128;
    int NP = out_size / F;                 // 50000

    const int threads = 256;               // 8 points per block
    int grid = (NP * 32 + threads - 1) / threads;
    pool_max_kernel<<<grid, threads, 0, stream>>>(
        (const float4*)features, nbr, (float4*)out, NP);
}

// Round 2
// 180.221 us; speedup vs baseline: 1.0696x; 1.0696x over previous
//
#include <hip/hip_runtime.h>
#include <math.h>

// Max-pool over gathered neighbor features, column-tiled for L2 locality.
//   features: (N, F=128) f32, neighbor_indices: (NP, K=32) i32
//   out: (NP, F=128) f32 = max over K of features[idx[p][k]][:]
//
// F is split into 4 chunks of 32 floats (one 128 B cache line per feature row
// per chunk). Each chunk is a separate sequential launch, so the per-pass
// gather working set is 12.8 MB instead of 51.2 MB -> higher L2 hit rate,
// fewer outstanding-miss-limited stalls.
//
// Within a chunk: 8 lanes per output point, lane l owns float4 #l of the
// 32-float chunk (8 x 16 B = 128 B, one full line per neighbor row).
// Each lane preloads 4 of the 32 neighbor indices as int4; per source lane we
// broadcast its 4 indices via __shfl width=8.

__global__ __launch_bounds__(256) void pool_max_chunk(
    const float4* __restrict__ feat4,   // (N, 32) rows of float4
    const int4*   __restrict__ nbr4,    // (NP, 8) rows of int4
    float4*       __restrict__ out4,    // (NP, 32)
    int NP, int chunk)
{
    int gid = blockIdx.x * blockDim.x + threadIdx.x;
    int p = gid >> 3;          // output point
    int l = gid & 7;           // lane within 8-lane group
    if (p >= NP) return;

    int4 myidx = nbr4[p * 8 + l];                    // 4 of this point's 32 indices
    const float4* fbase = feat4 + (size_t)chunk * 8 + l;

    float4 m = make_float4(-INFINITY, -INFINITY, -INFINITY, -INFINITY);
#pragma unroll
    for (int src = 0; src < 8; ++src) {
        int j0 = __shfl(myidx.x, src, 8);
        int j1 = __shfl(myidx.y, src, 8);
        int j2 = __shfl(myidx.z, src, 8);
        int j3 = __shfl(myidx.w, src, 8);
        float4 v0 = fbase[(size_t)j0 * 32];
        float4 v1 = fbase[(size_t)j1 * 32];
        float4 v2 = fbase[(size_t)j2 * 32];
        float4 v3 = fbase[(size_t)j3 * 32];
        m.x = fmaxf(fmaxf(fmaxf(m.x, v0.x), fmaxf(v1.x, v2.x)), v3.x);
        m.y = fmaxf(fmaxf(fmaxf(m.y, v0.y), fmaxf(v1.y, v2.y)), v3.y);
        m.z = fmaxf(fmaxf(fmaxf(m.z, v0.z), fmaxf(v1.z, v2.z)), v3.z);
        m.w = fmaxf(fmaxf(fmaxf(m.w, v0.w), fmaxf(v1.w, v2.w)), v3.w);
    }
    out4[(size_t)p * 32 + chunk * 8 + l] = m;
}

extern "C" void kernel_launch(void* const* d_in, const int* in_sizes, int n_in,
                              void* d_out, int out_size, void* d_ws, size_t ws_size,
                              hipStream_t stream) {
    // inputs: [0] points (N,3) f32 (unused), [1] features (N,128) f32,
    //         [2] neighbor_indices (NP,32) i32
    const float* features = (const float*)d_in[1];
    const int*   nbr      = (const int*)d_in[2];
    float*       out      = (float*)d_out;

    const int F = 128;
    int NP = out_size / F;                 // 50000

    const int threads = 256;               // 32 points per block (8 lanes/point)
    int grid = (NP * 8 + threads - 1) / threads;
    for (int chunk = 0; chunk < 4; ++chunk) {
        pool_max_chunk<<<grid, threads, 0, stream>>>(
            (const float4*)features, (const int4*)nbr, (float4*)out, NP, chunk);
    }
}